// Round 1
// 2532.599 us; speedup vs baseline: 1.0094x; 1.0094x over previous
//
#include <hip/hip_runtime.h>
#include <stdint.h>

// FlashGPTJAttention on MI355X (gfx950).
// Pipeline: cvt fp32->bf16 -> QKV B^T-GEMM (scatter epilogue to q/k/v [b][h][s][d])
//   -> RoPE(q,k) -> V transpose [b][h][d][s] -> scores B^T-GEMM (causal tile skip,
//   fp32) -> row softmax (probs bf16 in-place in scores rows) -> PV B^T-GEMM
//   (K-loop capped at diagonal) -> out-proj B^T-GEMM (fp32 -> d_out).
// R2: the two dense GEMMs (QKV, out-proj) moved from the m97 128-tile structure
// (733 TF, MfmaUtil 34%, barrier-drain bound) to a 256-tile deep-pipelined
// structure: BK=32, 4-deep circular LDS buffer, 8 waves (2Mx4N), counted
// s_waitcnt vmcnt(12) (never 0 in steady state), raw s_barrier, setprio around
// MFMA, XCD-aware block swizzle. Scores/PV stay on the 128-tile kernel.

typedef __bf16 bf16x8 __attribute__((ext_vector_type(8)));
typedef float f32x4 __attribute__((ext_vector_type(4)));

__device__ __forceinline__ unsigned short f2bf(float f) {
    union { float f; unsigned int u; } x;
    x.f = f;
    unsigned int r = x.u + 0x7fffu + ((x.u >> 16) & 1u);  // RNE
    return (unsigned short)(r >> 16);
}

__device__ __forceinline__ float bf2f(unsigned short h) {
    union { unsigned int u; float f; } x;
    x.u = ((unsigned int)h) << 16;
    return x.f;
}

__device__ __forceinline__ void gld16(const void* g, void* l) {
    __builtin_amdgcn_global_load_lds(
        (const __attribute__((address_space(1))) void*)g,
        (__attribute__((address_space(3))) void*)l, 16, 0, 0);
}

// ---------------------------------------------------------------------------
// fp32 -> bf16 convert, float4 loads / ushort4 stores, grid-stride
__global__ __launch_bounds__(256) void cvt_bf16(const float* __restrict__ src,
                                                unsigned short* __restrict__ dst,
                                                long n4) {
    long i = (long)blockIdx.x * 256 + threadIdx.x;
    long stride = (long)gridDim.x * 256;
    for (; i < n4; i += stride) {
        float4 v = ((const float4*)src)[i];
        ushort4 o;
        o.x = f2bf(v.x); o.y = f2bf(v.y); o.z = f2bf(v.z); o.w = f2bf(v.w);
        ((ushort4*)dst)[i] = o;
    }
}

// ---------------------------------------------------------------------------
// 256x256-tile B^T GEMM: C[m][n] = sum_k A[m][k]*B[n][k], bf16 inputs.
// 8 waves (2M x 4N), per-wave 128x64 output = 8x4 mfma_16x16x32 fragments.
// LDS: 4-slot circular buffer per matrix, slot = 256 rows x 32 K (16 KiB),
// total 128 KiB. Staging: 4 x global_load_lds(16B) per K-tile (A rows 0-127,
// A rows 128-255, B same), issued 3 K-tiles ahead. The per-tile wait is
// s_waitcnt vmcnt(12) = {t+1,t+2,t+3}'s 12 loads left in flight -> tile t
// drained; leading raw s_barrier publishes. stage(t+3) writes slot (t-1)&3,
// whose readers finished before iter t-1's trailing barrier. Tail: 12->8->4->0.
// Swizzle (proven-0-conflict algebra from the 128-tile kernel): physical 16B
// chunk = logical ^ ((row>>1)&3); inverse applied to the GLOBAL source address
// at staging (global_load_lds forces linear lane->LDS placement).
// EPI 0: QKV scatter -> q_s/k_s/v_s.  EPI 1: fp32 out-proj (N=4096) -> d_out.
template <int EPI>
__global__ __launch_bounds__(512, 2) void gemm256(
    const unsigned short* __restrict__ A, long lda,
    const unsigned short* __restrict__ B, long ldb,
    int nkt, void* __restrict__ out,
    unsigned short* __restrict__ out2, unsigned short* __restrict__ out3) {
    __shared__ __attribute__((aligned(16))) unsigned short As[4 * 8192];
    __shared__ __attribute__((aligned(16))) unsigned short Bs[4 * 8192];

    const int tid = threadIdx.x;
    const int gx = gridDim.x;
    const int bid = blockIdx.y * gx + blockIdx.x;
    const int cpx = (gx * gridDim.y) >> 3;  // blocks per XCD; grids are %8==0
    const int swz = (bid & 7) * cpx + (bid >> 3);
    const int ntile = swz % gx, mtile = swz / gx;

    const int l = tid & 63;
    const int wr = (tid >> 8) & 1, wc = (tid >> 6) & 3;  // wave (row, col)
    const int lr = l & 15, lg = l >> 4;

    // staging addressing: issue j covers rows j*128 + (tid>>2); 16B chunk
    // (tid&3) holds logical chunk (tid&3) ^ ((tid>>3)&3)  (inverse swizzle).
    const int srow = tid >> 2;
    const int slc = (tid & 3) ^ ((tid >> 3) & 3);
    const unsigned short* Ag = A + (long)(mtile * 256 + srow) * lda + slc * 8;
    const unsigned short* Bg = B + (long)(ntile * 256 + srow) * ldb + slc * 8;
    unsigned short* lA = As + tid * 8;
    unsigned short* lB = Bs + tid * 8;

#define STAGE256(kt)                                              \
    {                                                             \
        const int s_ = (kt) & 3;                                  \
        const unsigned short* a_ = Ag + (long)(kt) * 32;          \
        const unsigned short* b_ = Bg + (long)(kt) * 32;          \
        gld16(a_, lA + s_ * 8192);                                \
        gld16(a_ + 128 * lda, lA + s_ * 8192 + 4096);             \
        gld16(b_, lB + s_ * 8192);                                \
        gld16(b_ + 128 * ldb, lB + s_ * 8192 + 4096);             \
    }

    // fragment read offsets (elements within a slot), forward swizzle per row
    int aoff[8], boff[4];
#pragma unroll
    for (int i = 0; i < 8; ++i) {
        const int r = wr * 128 + i * 16 + lr;
        aoff[i] = r * 32 + ((lg ^ ((r >> 1) & 3)) << 3);
    }
#pragma unroll
    for (int i = 0; i < 4; ++i) {
        const int r = wc * 64 + i * 16 + lr;
        boff[i] = r * 32 + ((lg ^ ((r >> 1) & 3)) << 3);
    }

    f32x4 acc[8][4];
#pragma unroll
    for (int i = 0; i < 8; ++i)
#pragma unroll
        for (int j = 0; j < 4; ++j) acc[i][j] = (f32x4)(0.0f);

    // prologue: stage tiles 0..2 (12 loads in flight)
    STAGE256(0);
    STAGE256(1);
    STAGE256(2);

    for (int t = 0; t < nkt; ++t) {
        if (t + 3 < nkt) {
            STAGE256(t + 3);                                   // slot (t-1)&3
            asm volatile("s_waitcnt vmcnt(12)" ::: "memory");  // tile t landed
        } else if (t + 2 < nkt) {
            asm volatile("s_waitcnt vmcnt(8)" ::: "memory");
        } else if (t + 1 < nkt) {
            asm volatile("s_waitcnt vmcnt(4)" ::: "memory");
        } else {
            asm volatile("s_waitcnt vmcnt(0)" ::: "memory");   // final tile only
        }
        __builtin_amdgcn_s_barrier();        // publish tile t (raw: no drain)
        asm volatile("" ::: "memory");       // no LDS read hoists above barrier

        const unsigned short* as_ = As + ((t & 3) << 13);
        const unsigned short* bs_ = Bs + ((t & 3) << 13);
        bf16x8 af[8], bfr[4];
#pragma unroll
        for (int i = 0; i < 8; ++i) af[i] = *(const bf16x8*)(as_ + aoff[i]);
#pragma unroll
        for (int i = 0; i < 4; ++i) bfr[i] = *(const bf16x8*)(bs_ + boff[i]);

        __builtin_amdgcn_s_setprio(1);
#pragma unroll
        for (int mi = 0; mi < 8; ++mi)
#pragma unroll
            for (int ni = 0; ni < 4; ++ni)
                acc[mi][ni] = __builtin_amdgcn_mfma_f32_16x16x32_bf16(
                    af[mi], bfr[ni], acc[mi][ni], 0, 0, 0);
        __builtin_amdgcn_s_setprio(0);

        asm volatile("" ::: "memory");       // no LDS read sinks below barrier
        __builtin_amdgcn_s_barrier();        // slot t&3 free for stage(t+4)
        asm volatile("" ::: "memory");
    }
#undef STAGE256

    // epilogue: C/D layout col = lane&15, row = (lane>>4)*4 + reg
    const int mBase = mtile * 256 + wr * 128 + lg * 4;
    const int nBase = ntile * 256 + wc * 64 + lr;
#pragma unroll
    for (int mi = 0; mi < 8; ++mi) {
#pragma unroll
        for (int ni = 0; ni < 4; ++ni) {
#pragma unroll
            for (int r = 0; r < 4; ++r) {
                const int m = mBase + mi * 16 + r;
                const int n = nBase + ni * 16;
                const float v = acc[mi][ni][r];
                if (EPI == 0) {
                    const int which = n >> 12, h = (n >> 8) & 15, d = n & 255;
                    const int b = m >> 10, s = m & 1023;
                    const long idx = ((((long)b * 16 + h) << 10) + s) * 256 + d;
                    unsigned short* dst =
                        (which == 0) ? (unsigned short*)out : (which == 1 ? out2 : out3);
                    dst[idx] = f2bf(v);
                } else {
                    ((float*)out)[((long)m << 12) + n] = v;
                }
            }
        }
    }
}

// ---------------------------------------------------------------------------
// 128x128-tile B^T GEMM (m97 structure + XOR swizzle), kept for the small
// batched GEMMs: EPI 1 = scores (causal tile skip), EPI 2 = PV (K capped).
template <int EPI>
__global__ __launch_bounds__(256) void gemm_bt(
    const unsigned short* __restrict__ A, long astride, long abatch,
    const unsigned short* __restrict__ B, long bstride, long bbatch,
    int kIters, void* __restrict__ out,
    unsigned short* __restrict__ out2, unsigned short* __restrict__ out3) {
    const int tid = threadIdx.x;
    const int ntile = blockIdx.x, mtile = blockIdx.y, bz = blockIdx.z;
    if (EPI == 1 && ntile > mtile) return;  // causal: strictly-upper tiles
    int kit = kIters;
    if (EPI == 2) kit = (mtile + 1) * 4;    // causal cap: K up to diagonal tile

    __shared__ __attribute__((aligned(16))) unsigned short As[128 * 32];
    __shared__ __attribute__((aligned(16))) unsigned short Bs[128 * 32];

    const unsigned short* Ab = A + (long)bz * abatch + (long)mtile * 128 * astride;
    const unsigned short* Bb = B + (long)bz * bbatch + (long)ntile * 128 * bstride;

    const int w = tid >> 6, l = tid & 63;
    const int wm = (w >> 1) * 64, wn = (w & 1) * 64;
    const int lr = l & 15;
    const int lc = l >> 4;

    const int c0 = tid, c1 = tid + 256;
    const int r0 = c0 >> 2, r1 = c1 >> 2;
    const int lc0 = (c0 & 3) ^ ((r0 >> 1) & 3);
    const int lc1 = (c1 & 3) ^ ((r1 >> 1) & 3);
    const long a0 = (long)r0 * astride + lc0 * 8;
    const long a1 = (long)r1 * astride + lc1 * 8;
    const long b0 = (long)r0 * bstride + lc0 * 8;
    const long b1 = (long)r1 * bstride + lc1 * 8;

    int aoff[4], boff[4];
#pragma unroll
    for (int i = 0; i < 4; ++i) {
        const int ra = wm + i * 16 + lr;
        aoff[i] = ra * 32 + ((lc ^ ((ra >> 1) & 3)) << 3);
        const int rb = wn + i * 16 + lr;
        boff[i] = rb * 32 + ((lc ^ ((rb >> 1) & 3)) << 3);
    }

    f32x4 acc[4][4];
#pragma unroll
    for (int i = 0; i < 4; ++i)
#pragma unroll
        for (int j = 0; j < 4; ++j) acc[i][j] = (f32x4)(0.0f);

    for (int kt = 0; kt < kit; ++kt) {
        const unsigned short* ak = Ab + kt * 32;
        const unsigned short* bk = Bb + kt * 32;
        __syncthreads();
        gld16(ak + a0, As + (long)c0 * 8);
        gld16(ak + a1, As + (long)c1 * 8);
        gld16(bk + b0, Bs + (long)c0 * 8);
        gld16(bk + b1, Bs + (long)c1 * 8);
        __syncthreads();

        bf16x8 af[4], bfv[4];
#pragma unroll
        for (int i = 0; i < 4; ++i) {
            af[i] = *(const bf16x8*)(As + aoff[i]);
            bfv[i] = *(const bf16x8*)(Bs + boff[i]);
        }
#pragma unroll
        for (int mi = 0; mi < 4; ++mi)
#pragma unroll
            for (int ni = 0; ni < 4; ++ni)
                acc[mi][ni] = __builtin_amdgcn_mfma_f32_16x16x32_bf16(
                    af[mi], bfv[ni], acc[mi][ni], 0, 0, 0);
    }

    const int mBase = mtile * 128 + wm + (l >> 4) * 4;
    const int nBase = ntile * 128 + wn + (l & 15);
#pragma unroll
    for (int mi = 0; mi < 4; ++mi) {
#pragma unroll
        for (int ni = 0; ni < 4; ++ni) {
#pragma unroll
            for (int r = 0; r < 4; ++r) {
                const int m = mBase + mi * 16 + r;
                const int n = nBase + ni * 16;
                const float v = acc[mi][ni][r];
                if (EPI == 1) {
                    ((float*)out)[((long)bz << 20) + ((long)m << 10) + n] = v * 0.0625f;
                } else if (EPI == 2) {
                    const int b = bz >> 4, h = bz & 15;
                    ((unsigned short*)out)[(((long)b << 10) + m) * 4096 + h * 256 + n] =
                        f2bf(v);
                }
            }
        }
    }
    (void)out2; (void)out3;
}

// ---------------------------------------------------------------------------
// RoPE (GPT-NeoX rotate-half, rotary_dim=64) applied in place to q_s and k_s.
__global__ __launch_bounds__(256) void rope_qk(unsigned short* __restrict__ q_s,
                                               unsigned short* __restrict__ k_s,
                                               const float* __restrict__ cosp,
                                               const float* __restrict__ sinp) {
    const int tid = blockIdx.x * 256 + threadIdx.x;  // 8192*16*32 total
    const int i = tid & 31;
    const int h = (tid >> 5) & 15;
    const int tok = tid >> 9;
    const int b = tok >> 10, s = tok & 1023;
    const long base = ((((long)b * 16 + h) << 10) + s) * 256 + i;
    const float c = cosp[tok * 32 + i];
    const float sn = sinp[tok * 32 + i];
    {
        float x1 = bf2f(q_s[base]), x2 = bf2f(q_s[base + 32]);
        q_s[base] = f2bf(x1 * c - x2 * sn);
        q_s[base + 32] = f2bf(x2 * c + x1 * sn);
    }
    {
        float x1 = bf2f(k_s[base]), x2 = bf2f(k_s[base + 32]);
        k_s[base] = f2bf(x1 * c - x2 * sn);
        k_s[base + 32] = f2bf(x2 * c + x1 * sn);
    }
}

// ---------------------------------------------------------------------------
// V transpose per (b,h): [s][d] -> [d][s], 32x32 LDS tiles.
__global__ __launch_bounds__(256) void vtrans(const unsigned short* __restrict__ v_s,
                                              unsigned short* __restrict__ vT) {
    __shared__ unsigned short tile[32][33];
    const int bh = blockIdx.z;
    const int s0 = blockIdx.x * 32, d0 = blockIdx.y * 32;
    const int x = threadIdx.x, y = threadIdx.y;  // 32 x 8
    const unsigned short* src = v_s + (((long)bh << 10) + s0) * 256 + d0;
#pragma unroll
    for (int j = 0; j < 4; ++j) tile[y * 4 + j][x] = src[(y * 4 + j) * 256 + x];
    __syncthreads();
    unsigned short* dst = vT + (((long)bh << 8) + d0) * 1024 + s0;
#pragma unroll
    for (int j = 0; j < 4; ++j) dst[(y * 4 + j) * 1024 + x] = tile[x][y * 4 + j];
}

// ---------------------------------------------------------------------------
// Causal row softmax over scores[bh][q][0..q]; bf16 probs in place.
__global__ __launch_bounds__(256) void softmax_rows(float* __restrict__ scores) {
    const int row = blockIdx.x;           // 128*1024 rows
    const int bh = row >> 10, q = row & 1023;
    float* srow = scores + ((long)bh << 20) + ((long)q << 10);
    const int t = threadIdx.x;

    float v[4];
#pragma unroll
    for (int j = 0; j < 4; ++j) {
        const int k = t + (j << 8);
        v[j] = (k <= q) ? srow[k] : -3.0e38f;
    }
    float mx = fmaxf(fmaxf(v[0], v[1]), fmaxf(v[2], v[3]));
#pragma unroll
    for (int off = 32; off >= 1; off >>= 1) mx = fmaxf(mx, __shfl_xor(mx, off));
    __shared__ float redmax[4];
    if ((t & 63) == 0) redmax[t >> 6] = mx;
    __syncthreads();
    mx = fmaxf(fmaxf(redmax[0], redmax[1]), fmaxf(redmax[2], redmax[3]));

    float p[4];
    float s = 0.0f;
#pragma unroll
    for (int j = 0; j < 4; ++j) {
        const int k = t + (j << 8);
        p[j] = (k <= q) ? __expf(v[j] - mx) : 0.0f;
        s += p[j];
    }
#pragma unroll
    for (int off = 32; off >= 1; off >>= 1) s += __shfl_xor(s, off);
    __shared__ float redsum[4];
    if ((t & 63) == 0) redsum[t >> 6] = s;
    __syncthreads();
    s = redsum[0] + redsum[1] + redsum[2] + redsum[3];
    const float inv = 1.0f / s;

    unsigned short* prow = (unsigned short*)srow;
    const int kend = (q & ~127) + 128;  // diagonal-tile end
#pragma unroll
    for (int j = 0; j < 4; ++j) {
        const int k = t + (j << 8);
        if (k < kend) prow[k] = f2bf(p[j] * inv);
    }
}

// ---------------------------------------------------------------------------
extern "C" void kernel_launch(void* const* d_in, const int* in_sizes, int n_in,
                              void* d_out, int out_size, void* d_ws, size_t ws_size,
                              hipStream_t stream) {
    const float* hidden = (const float*)d_in[0];  // [8192][4096]
    const float* w_qkv  = (const float*)d_in[1];  // [12288][4096]
    const float* w_o    = (const float*)d_in[2];  // [4096][4096]
    const float* cosp   = (const float*)d_in[3];  // [8192][32]
    const float* sinp   = (const float*)d_in[4];  // [8192][32]
    // d_in[5..7]: key_cache / value_cache / slots — identity scatter+gather.

    const long SZ_WO = 33554432L, SZ_HEAD = 67108864L, SZ_SCORES = 536870912L;
    if (ws_size < (size_t)(SZ_WO + 5 * SZ_HEAD + SZ_SCORES)) return;
    char* p = (char*)d_ws;
    unsigned short* wo_b = (unsigned short*)p;  p += SZ_WO;
    unsigned short* q_s  = (unsigned short*)p;  p += SZ_HEAD;
    unsigned short* k_s  = (unsigned short*)p;  p += SZ_HEAD;
    unsigned short* v_s  = (unsigned short*)p;  p += SZ_HEAD;
    unsigned short* vT   = (unsigned short*)p;  p += SZ_HEAD;
    unsigned short* attn = (unsigned short*)p;  p += SZ_HEAD;
    char* X = p;
    unsigned short* hid_b  = (unsigned short*)X;
    unsigned short* wqkv_b = (unsigned short*)(X + SZ_HEAD);
    float* scores = (float*)X;

    // 1) converts
    cvt_bf16<<<8192, 256, 0, stream>>>(hidden, hid_b, (long)8192 * 4096 / 4);
    cvt_bf16<<<8192, 256, 0, stream>>>(w_qkv, wqkv_b, (long)12288 * 4096 / 4);
    cvt_bf16<<<4096, 256, 0, stream>>>(w_o, wo_b, (long)4096 * 4096 / 4);

    // 2) QKV GEMM: M=8192, N=12288, K=4096 (256-tile, nkt = 4096/32 = 128)
    gemm256<0><<<dim3(48, 32, 1), 512, 0, stream>>>(
        hid_b, 4096, wqkv_b, 4096, 128, q_s, k_s, v_s);

    // 3) RoPE on q,k
    rope_qk<<<16384, 256, 0, stream>>>(q_s, k_s, cosp, sinp);

    // 4) V transpose -> vT [bh][256][1024]
    vtrans<<<dim3(32, 8, 128), dim3(32, 8, 1), 0, stream>>>(v_s, vT);

    // 5) scores = q k^T / 16 per (b,h): M=N=1024, K=256, causal tile skip
    gemm_bt<1><<<dim3(8, 8, 128), 256, 0, stream>>>(
        q_s, 256, 262144, k_s, 256, 262144, 8, scores, nullptr, nullptr);

    // 6) softmax (in-place probs, bf16, row stride 2048 elems)
    softmax_rows<<<131072, 256, 0, stream>>>(scores);

    // 7) PV: A=probs (stride 2048, batch 1024*2048), B^T=vT, N=256
    gemm_bt<2><<<dim3(2, 8, 128), 256, 0, stream>>>(
        (unsigned short*)scores, 2048, 2097152, vT, 1024, 262144, 0,
        attn, nullptr, nullptr);

    // 8) out-proj: M=8192, N=4096, K=4096 -> fp32 d_out (256-tile)
    gemm256<1><<<dim3(16, 32, 1), 512, 0, stream>>>(
        attn, 4096, wo_b, 4096, 128, d_out, nullptr, nullptr);

    (void)in_sizes; (void)n_in; (void)out_size;
}

// Round 2
// 2227.839 us; speedup vs baseline: 1.1474x; 1.1368x over previous
//
#include <hip/hip_runtime.h>
#include <stdint.h>

// FlashGPTJAttention on MI355X (gfx950).
// Pipeline: cvt fp32->bf16 -> QKV B^T-GEMM (scatter epilogue to q/k/v [b][h][s][d])
//   -> RoPE(q,k) -> V transpose [b][h][d][s] -> scores B^T-GEMM (causal tile skip,
//   fp32) -> row softmax (probs bf16 in-place in scores rows) -> PV B^T-GEMM
//   (K-loop capped at diagonal) -> out-proj B^T-GEMM (fp32 -> d_out).
// R2 post-mortem: R1's monolithic-per-tile loop with counted vmcnt was a
// "2-phase" schedule -> 754 TF (2-phase class). R3: true phased schedule
// (m201-style): BK=64, 2-deep dbuf split into 4 half-tiles, 4 phases/K-tile,
// each phase = {stage 1 half-tile, vmcnt(12), barrier, ds_read subtile,
// 16 MFMA with setprio, lgkmcnt(0), barrier}. Stage->read distance >= 6 phases.
// Half-tile death ledger: ph0(t) reads AK0/BK0(t); ph1 reads BK0; ph2 reads
// AK1/BK1; ph3 reads BK1. Stages: ph0(t)->BK1(t+1) [dead since ph3(t-1)],
// ph1(t)->AK0(t+2) [dead after ph0(t)], ph2(t)->BK0(t+2) [after ph1],
// ph3(t)->AK1(t+2) [after ph2]. Steady-state waits drain 14->12 loads; the
// half landing at each wait is exactly the one first read in that phase.

typedef __bf16 bf16x8 __attribute__((ext_vector_type(8)));
typedef float f32x4 __attribute__((ext_vector_type(4)));

__device__ __forceinline__ unsigned short f2bf(float f) {
    union { float f; unsigned int u; } x;
    x.f = f;
    unsigned int r = x.u + 0x7fffu + ((x.u >> 16) & 1u);  // RNE
    return (unsigned short)(r >> 16);
}

__device__ __forceinline__ float bf2f(unsigned short h) {
    union { unsigned int u; float f; } x;
    x.u = ((unsigned int)h) << 16;
    return x.f;
}

__device__ __forceinline__ void gld16(const void* g, void* l) {
    __builtin_amdgcn_global_load_lds(
        (const __attribute__((address_space(1))) void*)g,
        (__attribute__((address_space(3))) void*)l, 16, 0, 0);
}

// ---------------------------------------------------------------------------
// fp32 -> bf16 convert, float4 loads / ushort4 stores, grid-stride
__global__ __launch_bounds__(256) void cvt_bf16(const float* __restrict__ src,
                                                unsigned short* __restrict__ dst,
                                                long n4) {
    long i = (long)blockIdx.x * 256 + threadIdx.x;
    long stride = (long)gridDim.x * 256;
    for (; i < n4; i += stride) {
        float4 v = ((const float4*)src)[i];
        ushort4 o;
        o.x = f2bf(v.x); o.y = f2bf(v.y); o.z = f2bf(v.z); o.w = f2bf(v.w);
        ((ushort4*)dst)[i] = o;
    }
}

// ---------------------------------------------------------------------------
// Phased 256x256-tile B^T GEMM: C[m][n] = sum_k A[m][k]*B[n][k], bf16 in.
// 8 waves (2M x 4N), per-wave 128x64 output = 8x4 mfma_16x16x32 fragments.
// LDS 128 KiB: per matrix 2 buffers x 2 K-halves x [256 rows][32 K] bf16.
// XOR chunk swizzle within each [256][32] region (same algebra as proven
// kernel): logical 16B chunk c of row r at physical c ^ ((r>>1)&3); inverse
// applied to the GLOBAL source (global_load_lds forces linear placement).
// EPI 0: QKV scatter -> q_s/k_s/v_s.  EPI 1: fp32 (N=4096) -> d_out.
template <int EPI>
__global__ __launch_bounds__(512, 2) void gemm256p(
    const unsigned short* __restrict__ A, long lda,
    const unsigned short* __restrict__ B, long ldb,
    int nkt, void* __restrict__ out,
    unsigned short* __restrict__ out2, unsigned short* __restrict__ out3) {
    __shared__ __attribute__((aligned(16))) unsigned short As[32768];
    __shared__ __attribute__((aligned(16))) unsigned short Bs[32768];

    const int tid = threadIdx.x;
    const int gx = gridDim.x;
    const int bid = blockIdx.y * gx + blockIdx.x;
    const int cpx = (gx * gridDim.y) >> 3;  // blocks per XCD; grids are %8==0
    const int swz = (bid & 7) * cpx + (bid >> 3);
    const int ntile = swz % gx, mtile = swz / gx;

    const int l = tid & 63;
    const int wr = (tid >> 8) & 1, wc = (tid >> 6) & 3;  // wave (row, col)
    const int lr = l & 15, lg = l >> 4;

    // staging: thread covers 16B chunks {tid, tid+512} of each 16 KiB half
    // (row = chunk>>2 in 0..255); physical chunk (tid&3) holds logical chunk
    // (tid&3)^((row>>1)&3); row+128 has the same swizzle bits (128%8==0 rows).
    const int srow = tid >> 2;
    const int slc = (tid & 3) ^ ((tid >> 3) & 3);
    const unsigned short* Ag = A + (long)(mtile * 256 + srow) * lda + slc * 8;
    const unsigned short* Bg = B + (long)(ntile * 256 + srow) * ldb + slc * 8;
    unsigned short* lAs = As + tid * 8;
    unsigned short* lBs = Bs + tid * 8;

    // region offset (elems): buffer (t&1)*16384 + kk*8192
#define STAGE_A(t, kk)                                                 \
    {                                                                  \
        const unsigned short* g_ = Ag + (long)(t) * 64 + (kk) * 32;    \
        unsigned short* d_ = lAs + (((t) & 1) * 16384 + (kk) * 8192);  \
        gld16(g_, d_);                                                 \
        gld16(g_ + 128 * lda, d_ + 4096);                              \
    }
#define STAGE_B(t, kk)                                                 \
    {                                                                  \
        const unsigned short* g_ = Bg + (long)(t) * 64 + (kk) * 32;    \
        unsigned short* d_ = lBs + (((t) & 1) * 16384 + (kk) * 8192);  \
        gld16(g_, d_);                                                 \
        gld16(g_ + 128 * ldb, d_ + 4096);                              \
    }
#define WAITV(full_)                                                   \
    if (full_) { asm volatile("s_waitcnt vmcnt(12)" ::: "memory"); }   \
    else       { asm volatile("s_waitcnt vmcnt(0)" ::: "memory"); }
#define LEADBAR()                                                      \
    __builtin_amdgcn_s_barrier();                                      \
    __builtin_amdgcn_sched_barrier(0)
#define TRAILBAR()                                                     \
    asm volatile("s_waitcnt lgkmcnt(0)" ::: "memory");                 \
    __builtin_amdgcn_sched_barrier(0);                                 \
    __builtin_amdgcn_s_barrier()

    // fragment read offsets (elems within a [256][32] region), fwd swizzle
    int aoff[8], boff[4];
#pragma unroll
    for (int i = 0; i < 8; ++i) {
        const int r = wr * 128 + i * 16 + lr;
        aoff[i] = r * 32 + ((lg ^ ((r >> 1) & 3)) << 3);
    }
#pragma unroll
    for (int i = 0; i < 4; ++i) {
        const int r = wc * 64 + i * 16 + lr;
        boff[i] = r * 32 + ((lg ^ ((r >> 1) & 3)) << 3);
    }

    f32x4 acc[8][4];
#pragma unroll
    for (int i = 0; i < 8; ++i)
#pragma unroll
        for (int j = 0; j < 4; ++j) acc[i][j] = (f32x4)(0.0f);

    // prologue: tile0 fully + tile1's first 3 halves, in deadline order
    STAGE_A(0, 0); STAGE_B(0, 0); STAGE_A(0, 1); STAGE_B(0, 1);
    STAGE_A(1, 0); STAGE_B(1, 0); STAGE_A(1, 1);   // 14 loads in flight

    for (int t = 0; t < nkt; ++t) {
        const int p = t & 1;
        const unsigned short* a0 = As + p * 16384;         // A kk=0
        const unsigned short* b0 = Bs + p * 16384;         // B kk=0
        const unsigned short* a1 = a0 + 8192;              // A kk=1
        const unsigned short* b1 = b0 + 8192;              // B kk=1
        const bool full = (t + 2 < nkt);

        bf16x8 af[8];

        // ---- phase 0: kk=0, ni 0-1 (reads AK0, BK0)
        if (t + 1 < nkt) STAGE_B(t + 1, 1);
        WAITV(full);
        LEADBAR();
        {
#pragma unroll
            for (int mi = 0; mi < 8; ++mi)
                af[mi] = *(const bf16x8*)(a0 + aoff[mi]);
            bf16x8 f0 = *(const bf16x8*)(b0 + boff[0]);
            bf16x8 f1 = *(const bf16x8*)(b0 + boff[1]);
            __builtin_amdgcn_s_setprio(1);
#pragma unroll
            for (int mi = 0; mi < 8; ++mi)
                acc[mi][0] = __builtin_amdgcn_mfma_f32_16x16x32_bf16(
                    af[mi], f0, acc[mi][0], 0, 0, 0);
#pragma unroll
            for (int mi = 0; mi < 8; ++mi)
                acc[mi][1] = __builtin_amdgcn_mfma_f32_16x16x32_bf16(
                    af[mi], f1, acc[mi][1], 0, 0, 0);
            __builtin_amdgcn_s_setprio(0);
        }
        TRAILBAR();

        // ---- phase 1: kk=0, ni 2-3 (reads BK0; af reused)
        if (full) STAGE_A(t + 2, 0);
        WAITV(full);
        LEADBAR();
        {
            bf16x8 f2 = *(const bf16x8*)(b0 + boff[2]);
            bf16x8 f3 = *(const bf16x8*)(b0 + boff[3]);
            __builtin_amdgcn_s_setprio(1);
#pragma unroll
            for (int mi = 0; mi < 8; ++mi)
                acc[mi][2] = __builtin_amdgcn_mfma_f32_16x16x32_bf16(
                    af[mi], f2, acc[mi][2], 0, 0, 0);
#pragma unroll
            for (int mi = 0; mi < 8; ++mi)
                acc[mi][3] = __builtin_amdgcn_mfma_f32_16x16x32_bf16(
                    af[mi], f3, acc[mi][3], 0, 0, 0);
            __builtin_amdgcn_s_setprio(0);
        }
        TRAILBAR();

        // ---- phase 2: kk=1, ni 0-1 (reads AK1, BK1)
        if (full) STAGE_B(t + 2, 0);
        WAITV(full);
        LEADBAR();
        {
#pragma unroll
            for (int mi = 0; mi < 8; ++mi)
                af[mi] = *(const bf16x8*)(a1 + aoff[mi]);
            bf16x8 f0 = *(const bf16x8*)(b1 + boff[0]);
            bf16x8 f1 = *(const bf16x8*)(b1 + boff[1]);
            __builtin_amdgcn_s_setprio(1);
#pragma unroll
            for (int mi = 0; mi < 8; ++mi)
                acc[mi][0] = __builtin_amdgcn_mfma_f32_16x16x32_bf16(
                    af[mi], f0, acc[mi][0], 0, 0, 0);
#pragma unroll
            for (int mi = 0; mi < 8; ++mi)
                acc[mi][1] = __builtin_amdgcn_mfma_f32_16x16x32_bf16(
                    af[mi], f1, acc[mi][1], 0, 0, 0);
            __builtin_amdgcn_s_setprio(0);
        }
        TRAILBAR();

        // ---- phase 3: kk=1, ni 2-3 (reads BK1; af reused)
        if (full) STAGE_A(t + 2, 1);
        WAITV(full);
        LEADBAR();
        {
            bf16x8 f2 = *(const bf16x8*)(b1 + boff[2]);
            bf16x8 f3 = *(const bf16x8*)(b1 + boff[3]);
            __builtin_amdgcn_s_setprio(1);
#pragma unroll
            for (int mi = 0; mi < 8; ++mi)
                acc[mi][2] = __builtin_amdgcn_mfma_f32_16x16x32_bf16(
                    af[mi], f2, acc[mi][2], 0, 0, 0);
#pragma unroll
            for (int mi = 0; mi < 8; ++mi)
                acc[mi][3] = __builtin_amdgcn_mfma_f32_16x16x32_bf16(
                    af[mi], f3, acc[mi][3], 0, 0, 0);
            __builtin_amdgcn_s_setprio(0);
        }
        TRAILBAR();
    }
#undef STAGE_A
#undef STAGE_B
#undef WAITV
#undef LEADBAR
#undef TRAILBAR

    // epilogue: C/D layout col = lane&15, row = (lane>>4)*4 + reg
    const int mBase = mtile * 256 + wr * 128 + lg * 4;
    const int nBase = ntile * 256 + wc * 64 + lr;
#pragma unroll
    for (int mi = 0; mi < 8; ++mi) {
#pragma unroll
        for (int ni = 0; ni < 4; ++ni) {
#pragma unroll
            for (int r = 0; r < 4; ++r) {
                const int m = mBase + mi * 16 + r;
                const int n = nBase + ni * 16;
                const float v = acc[mi][ni][r];
                if (EPI == 0) {
                    const int which = n >> 12, h = (n >> 8) & 15, d = n & 255;
                    const int b = m >> 10, s = m & 1023;
                    const long idx = ((((long)b * 16 + h) << 10) + s) * 256 + d;
                    unsigned short* dst =
                        (which == 0) ? (unsigned short*)out : (which == 1 ? out2 : out3);
                    dst[idx] = f2bf(v);
                } else {
                    ((float*)out)[((long)m << 12) + n] = v;
                }
            }
        }
    }
}

// ---------------------------------------------------------------------------
// 128x128-tile B^T GEMM (m97 structure + XOR swizzle), kept for the small
// batched GEMMs: EPI 1 = scores (causal tile skip), EPI 2 = PV (K capped).
template <int EPI>
__global__ __launch_bounds__(256) void gemm_bt(
    const unsigned short* __restrict__ A, long astride, long abatch,
    const unsigned short* __restrict__ B, long bstride, long bbatch,
    int kIters, void* __restrict__ out,
    unsigned short* __restrict__ out2, unsigned short* __restrict__ out3) {
    const int tid = threadIdx.x;
    const int ntile = blockIdx.x, mtile = blockIdx.y, bz = blockIdx.z;
    if (EPI == 1 && ntile > mtile) return;  // causal: strictly-upper tiles
    int kit = kIters;
    if (EPI == 2) kit = (mtile + 1) * 4;    // causal cap: K up to diagonal tile

    __shared__ __attribute__((aligned(16))) unsigned short As[128 * 32];
    __shared__ __attribute__((aligned(16))) unsigned short Bs[128 * 32];

    const unsigned short* Ab = A + (long)bz * abatch + (long)mtile * 128 * astride;
    const unsigned short* Bb = B + (long)bz * bbatch + (long)ntile * 128 * bstride;

    const int w = tid >> 6, l = tid & 63;
    const int wm = (w >> 1) * 64, wn = (w & 1) * 64;
    const int lr = l & 15;
    const int lc = l >> 4;

    const int c0 = tid, c1 = tid + 256;
    const int r0 = c0 >> 2, r1 = c1 >> 2;
    const int lc0 = (c0 & 3) ^ ((r0 >> 1) & 3);
    const int lc1 = (c1 & 3) ^ ((r1 >> 1) & 3);
    const long a0 = (long)r0 * astride + lc0 * 8;
    const long a1 = (long)r1 * astride + lc1 * 8;
    const long b0 = (long)r0 * bstride + lc0 * 8;
    const long b1 = (long)r1 * bstride + lc1 * 8;

    int aoff[4], boff[4];
#pragma unroll
    for (int i = 0; i < 4; ++i) {
        const int ra = wm + i * 16 + lr;
        aoff[i] = ra * 32 + ((lc ^ ((ra >> 1) & 3)) << 3);
        const int rb = wn + i * 16 + lr;
        boff[i] = rb * 32 + ((lc ^ ((rb >> 1) & 3)) << 3);
    }

    f32x4 acc[4][4];
#pragma unroll
    for (int i = 0; i < 4; ++i)
#pragma unroll
        for (int j = 0; j < 4; ++j) acc[i][j] = (f32x4)(0.0f);

    for (int kt = 0; kt < kit; ++kt) {
        const unsigned short* ak = Ab + kt * 32;
        const unsigned short* bk = Bb + kt * 32;
        __syncthreads();
        gld16(ak + a0, As + (long)c0 * 8);
        gld16(ak + a1, As + (long)c1 * 8);
        gld16(bk + b0, Bs + (long)c0 * 8);
        gld16(bk + b1, Bs + (long)c1 * 8);
        __syncthreads();

        bf16x8 af[4], bfv[4];
#pragma unroll
        for (int i = 0; i < 4; ++i) {
            af[i] = *(const bf16x8*)(As + aoff[i]);
            bfv[i] = *(const bf16x8*)(Bs + boff[i]);
        }
#pragma unroll
        for (int mi = 0; mi < 4; ++mi)
#pragma unroll
            for (int ni = 0; ni < 4; ++ni)
                acc[mi][ni] = __builtin_amdgcn_mfma_f32_16x16x32_bf16(
                    af[mi], bfv[ni], acc[mi][ni], 0, 0, 0);
    }

    const int mBase = mtile * 128 + wm + (l >> 4) * 4;
    const int nBase = ntile * 128 + wn + (l & 15);
#pragma unroll
    for (int mi = 0; mi < 4; ++mi) {
#pragma unroll
        for (int ni = 0; ni < 4; ++ni) {
#pragma unroll
            for (int r = 0; r < 4; ++r) {
                const int m = mBase + mi * 16 + r;
                const int n = nBase + ni * 16;
                const float v = acc[mi][ni][r];
                if (EPI == 1) {
                    ((float*)out)[((long)bz << 20) + ((long)m << 10) + n] = v * 0.0625f;
                } else if (EPI == 2) {
                    const int b = bz >> 4, h = bz & 15;
                    ((unsigned short*)out)[(((long)b << 10) + m) * 4096 + h * 256 + n] =
                        f2bf(v);
                }
            }
        }
    }
    (void)out2; (void)out3;
}

// ---------------------------------------------------------------------------
// RoPE (GPT-NeoX rotate-half, rotary_dim=64) applied in place to q_s and k_s.
__global__ __launch_bounds__(256) void rope_qk(unsigned short* __restrict__ q_s,
                                               unsigned short* __restrict__ k_s,
                                               const float* __restrict__ cosp,
                                               const float* __restrict__ sinp) {
    const int tid = blockIdx.x * 256 + threadIdx.x;  // 8192*16*32 total
    const int i = tid & 31;
    const int h = (tid >> 5) & 15;
    const int tok = tid >> 9;
    const int b = tok >> 10, s = tok & 1023;
    const long base = ((((long)b * 16 + h) << 10) + s) * 256 + i;
    const float c = cosp[tok * 32 + i];
    const float sn = sinp[tok * 32 + i];
    {
        float x1 = bf2f(q_s[base]), x2 = bf2f(q_s[base + 32]);
        q_s[base] = f2bf(x1 * c - x2 * sn);
        q_s[base + 32] = f2bf(x2 * c + x1 * sn);
    }
    {
        float x1 = bf2f(k_s[base]), x2 = bf2f(k_s[base + 32]);
        k_s[base] = f2bf(x1 * c - x2 * sn);
        k_s[base + 32] = f2bf(x2 * c + x1 * sn);
    }
}

// ---------------------------------------------------------------------------
// V transpose per (b,h): [s][d] -> [d][s], 32x32 LDS tiles.
__global__ __launch_bounds__(256) void vtrans(const unsigned short* __restrict__ v_s,
                                              unsigned short* __restrict__ vT) {
    __shared__ unsigned short tile[32][33];
    const int bh = blockIdx.z;
    const int s0 = blockIdx.x * 32, d0 = blockIdx.y * 32;
    const int x = threadIdx.x, y = threadIdx.y;  // 32 x 8
    const unsigned short* src = v_s + (((long)bh << 10) + s0) * 256 + d0;
#pragma unroll
    for (int j = 0; j < 4; ++j) tile[y * 4 + j][x] = src[(y * 4 + j) * 256 + x];
    __syncthreads();
    unsigned short* dst = vT + (((long)bh << 8) + d0) * 1024 + s0;
#pragma unroll
    for (int j = 0; j < 4; ++j) dst[(y * 4 + j) * 1024 + x] = tile[x][y * 4 + j];
}

// ---------------------------------------------------------------------------
// Causal row softmax over scores[bh][q][0..q]; bf16 probs in place.
__global__ __launch_bounds__(256) void softmax_rows(float* __restrict__ scores) {
    const int row = blockIdx.x;           // 128*1024 rows
    const int bh = row >> 10, q = row & 1023;
    float* srow = scores + ((long)bh << 20) + ((long)q << 10);
    const int t = threadIdx.x;

    float v[4];
#pragma unroll
    for (int j = 0; j < 4; ++j) {
        const int k = t + (j << 8);
        v[j] = (k <= q) ? srow[k] : -3.0e38f;
    }
    float mx = fmaxf(fmaxf(v[0], v[1]), fmaxf(v[2], v[3]));
#pragma unroll
    for (int off = 32; off >= 1; off >>= 1) mx = fmaxf(mx, __shfl_xor(mx, off));
    __shared__ float redmax[4];
    if ((t & 63) == 0) redmax[t >> 6] = mx;
    __syncthreads();
    mx = fmaxf(fmaxf(redmax[0], redmax[1]), fmaxf(redmax[2], redmax[3]));

    float p[4];
    float s = 0.0f;
#pragma unroll
    for (int j = 0; j < 4; ++j) {
        const int k = t + (j << 8);
        p[j] = (k <= q) ? __expf(v[j] - mx) : 0.0f;
        s += p[j];
    }
#pragma unroll
    for (int off = 32; off >= 1; off >>= 1) s += __shfl_xor(s, off);
    __shared__ float redsum[4];
    if ((t & 63) == 0) redsum[t >> 6] = s;
    __syncthreads();
    s = redsum[0] + redsum[1] + redsum[2] + redsum[3];
    const float inv = 1.0f / s;

    unsigned short* prow = (unsigned short*)srow;
    const int kend = (q & ~127) + 128;  // diagonal-tile end
#pragma unroll
    for (int j = 0; j < 4; ++j) {
        const int k = t + (j << 8);
        if (k < kend) prow[k] = f2bf(p[j] * inv);
    }
}

// ---------------------------------------------------------------------------
extern "C" void kernel_launch(void* const* d_in, const int* in_sizes, int n_in,
                              void* d_out, int out_size, void* d_ws, size_t ws_size,
                              hipStream_t stream) {
    const float* hidden = (const float*)d_in[0];  // [8192][4096]
    const float* w_qkv  = (const float*)d_in[1];  // [12288][4096]
    const float* w_o    = (const float*)d_in[2];  // [4096][4096]
    const float* cosp   = (const float*)d_in[3];  // [8192][32]
    const float* sinp   = (const float*)d_in[4];  // [8192][32]
    // d_in[5..7]: key_cache / value_cache / slots — identity scatter+gather.

    const long SZ_WO = 33554432L, SZ_HEAD = 67108864L, SZ_SCORES = 536870912L;
    if (ws_size < (size_t)(SZ_WO + 5 * SZ_HEAD + SZ_SCORES)) return;
    char* p = (char*)d_ws;
    unsigned short* wo_b = (unsigned short*)p;  p += SZ_WO;
    unsigned short* q_s  = (unsigned short*)p;  p += SZ_HEAD;
    unsigned short* k_s  = (unsigned short*)p;  p += SZ_HEAD;
    unsigned short* v_s  = (unsigned short*)p;  p += SZ_HEAD;
    unsigned short* vT   = (unsigned short*)p;  p += SZ_HEAD;
    unsigned short* attn = (unsigned short*)p;  p += SZ_HEAD;
    char* X = p;
    unsigned short* hid_b  = (unsigned short*)X;
    unsigned short* wqkv_b = (unsigned short*)(X + SZ_HEAD);
    float* scores = (float*)X;

    // 1) converts
    cvt_bf16<<<8192, 256, 0, stream>>>(hidden, hid_b, (long)8192 * 4096 / 4);
    cvt_bf16<<<8192, 256, 0, stream>>>(w_qkv, wqkv_b, (long)12288 * 4096 / 4);
    cvt_bf16<<<4096, 256, 0, stream>>>(w_o, wo_b, (long)4096 * 4096 / 4);

    // 2) QKV GEMM: M=8192, N=12288, K=4096 (256-tile phased, nkt = 4096/64)
    gemm256p<0><<<dim3(48, 32, 1), 512, 0, stream>>>(
        hid_b, 4096, wqkv_b, 4096, 64, q_s, k_s, v_s);

    // 3) RoPE on q,k
    rope_qk<<<16384, 256, 0, stream>>>(q_s, k_s, cosp, sinp);

    // 4) V transpose -> vT [bh][256][1024]
    vtrans<<<dim3(32, 8, 128), dim3(32, 8, 1), 0, stream>>>(v_s, vT);

    // 5) scores = q k^T / 16 per (b,h): M=N=1024, K=256, causal tile skip
    gemm_bt<1><<<dim3(8, 8, 128), 256, 0, stream>>>(
        q_s, 256, 262144, k_s, 256, 262144, 8, scores, nullptr, nullptr);

    // 6) softmax (in-place probs, bf16, row stride 2048 elems)
    softmax_rows<<<131072, 256, 0, stream>>>(scores);

    // 7) PV: A=probs (stride 2048, batch 1024*2048), B^T=vT, N=256
    gemm_bt<2><<<dim3(2, 8, 128), 256, 0, stream>>>(
        (unsigned short*)scores, 2048, 2097152, vT, 1024, 262144, 0,
        attn, nullptr, nullptr);

    // 8) out-proj: M=8192, N=4096, K=4096 -> fp32 d_out (256-tile phased)
    gemm256p<1><<<dim3(16, 32, 1), 512, 0, stream>>>(
        attn, 4096, wo_b, 4096, 64, d_out, nullptr, nullptr);

    (void)in_sizes; (void)n_in; (void)out_size;
}